// Round 4
// baseline (1115.926 us; speedup 1.0000x reference)
//
#include <hip/hip_runtime.h>
#include <hip/hip_bf16.h>

// Problem constants (fixed by reference): B=64, C=32, V=1024, L=12, ORDER=2
// Decomposition:
//   adp = softmax(relu(nv1@nv2), axis=1)
//   Bt_cat[6][1024][1024] bf16:  slice k, row w, col v = G_k[v][w]
//     G = {A1, A1^2, A2, A2^2, adp, adp^2}
//   xT bf16 rows m=(b*12+l)*32+c, cols v   (row-major K=1024)
//   R[m,(k,w)] = sum_v xT[m,v]*G_k[v,w]  stored in layout [b][l][k][c][w] bf16
//   out[b,o,w,l] = bias[o] + sum_c W[o,c]*x[b,c,w,l] + sum_{k,c} W[o,32(k+1)+c]*R_k[b,c,w,l]
//
// R5 change: mix_kernel was the hidden giant (~350 of 758 us): its weight
// reads Wp[c*32+o] were per-lane LDS broadcasts -> 16 waves x 7840 ds_reads
// x 5.8cyc ~= 300us of serialized LDS pipe per CU. Weights are wave-uniform,
// so: (a) new transpose_w kernel writes Wt[kc][o] fp32 into the dead As
// region; (b) mix reads weights from global via uniform float4 loads
// (scalarizes to s_load / L1-hot) -- zero LDS weight traffic; (c) Wl LDS
// freed -> 48 KB -> 3 blocks/CU. Numerically identical summation.
// Also: transpose_x_k stores vectorized (ushort4). gemm256 untouched (R4).

typedef __attribute__((ext_vector_type(8))) short short8;
typedef __attribute__((ext_vector_type(4))) float floatx4;

#define V_DIM 1024
#define L_DIM 12
#define B_DIM 64
#define C_DIM 32

// ---------------- adp: relu + row softmax --------------------------------
__global__ __launch_bounds__(128) void adp_kernel(
    const float* __restrict__ nv1, const float* __restrict__ nv2,
    float* __restrict__ adp) {
  const int v = blockIdx.x, tid = threadIdx.x;
  float n1[10];
#pragma unroll
  for (int i = 0; i < 10; ++i) n1[i] = nv1[v * 10 + i];
  __shared__ float red[128];
  float e[8];
  float lmax = -1e30f;
#pragma unroll
  for (int j = 0; j < 8; ++j) {
    int w = tid + j * 128;
    float s = 0.f;
#pragma unroll
    for (int i = 0; i < 10; ++i) s += n1[i] * nv2[i * V_DIM + w];
    s = fmaxf(s, 0.f);
    e[j] = s;
    lmax = fmaxf(lmax, s);
  }
  red[tid] = lmax; __syncthreads();
  for (int s = 64; s > 0; s >>= 1) {
    if (tid < s) red[tid] = fmaxf(red[tid], red[tid + s]);
    __syncthreads();
  }
  float mx = red[0]; __syncthreads();
  float lsum = 0.f;
#pragma unroll
  for (int j = 0; j < 8; ++j) { e[j] = __expf(e[j] - mx); lsum += e[j]; }
  red[tid] = lsum; __syncthreads();
  for (int s = 64; s > 0; s >>= 1) {
    if (tid < s) red[tid] += red[tid + s];
    __syncthreads();
  }
  float inv = 1.f / red[0];
#pragma unroll
  for (int j = 0; j < 8; ++j) adp[(size_t)v * V_DIM + tid + j * 128] = e[j] * inv;
}

// ------------- cast supports to bf16: straight + transposed ---------------
__global__ __launch_bounds__(256) void cast_transpose(
    const float* __restrict__ A1, const float* __restrict__ A2,
    const float* __restrict__ adp, __hip_bfloat16* __restrict__ As,
    __hip_bfloat16* __restrict__ BtCat) {
  const int z = blockIdx.z;
  const float* src = (z == 0) ? A1 : (z == 1) ? A2 : adp;
  __hip_bfloat16* sdst = As + (size_t)z * V_DIM * V_DIM;
  __hip_bfloat16* tdst = BtCat + (size_t)(2 * z) * V_DIM * V_DIM;
  __shared__ float tile[64][65];
  const int v0 = blockIdx.y * 64, w0 = blockIdx.x * 64;
  const int tc = threadIdx.x & 15, tr = threadIdx.x >> 4;
#pragma unroll
  for (int i = 0; i < 4; ++i) {
    int r = tr + i * 16;
    float4 val = *(const float4*)(src + (size_t)(v0 + r) * V_DIM + w0 + tc * 4);
    tile[r][tc * 4 + 0] = val.x; tile[r][tc * 4 + 1] = val.y;
    tile[r][tc * 4 + 2] = val.z; tile[r][tc * 4 + 3] = val.w;
    __hip_bfloat16* sp = sdst + (size_t)(v0 + r) * V_DIM + w0 + tc * 4;
    sp[0] = __float2bfloat16(val.x); sp[1] = __float2bfloat16(val.y);
    sp[2] = __float2bfloat16(val.z); sp[3] = __float2bfloat16(val.w);
  }
  __syncthreads();
#pragma unroll
  for (int i = 0; i < 4; ++i) {
    int r = tr + i * 16;  // output row = w0 + r
    __hip_bfloat16* tp = tdst + (size_t)(w0 + r) * V_DIM + v0 + tc * 4;
#pragma unroll
    for (int j = 0; j < 4; ++j) tp[j] = __float2bfloat16(tile[tc * 4 + j][r]);
  }
}

// ------------- x [B,C,V,L] fp32 -> xT bf16 rows (b*12+l)*32+c -------------
__global__ __launch_bounds__(256) void transpose_x_k(
    const float* __restrict__ x, __hip_bfloat16* __restrict__ xT) {
  const int bc = blockIdx.x;         // b*32+c
  const int b = bc >> 5, c = bc & 31;
  __shared__ __align__(16) __hip_bfloat16 tile[V_DIM * L_DIM];  // idx v*12+l
  const float4* src = (const float4*)(x + (size_t)bc * (V_DIM * L_DIM));
#pragma unroll
  for (int i = 0; i < 12; ++i) {
    int idx = threadIdx.x + i * 256;  // 3072 float4
    float4 v = src[idx];
    int e = idx * 4;
    tile[e + 0] = __float2bfloat16(v.x); tile[e + 1] = __float2bfloat16(v.y);
    tile[e + 2] = __float2bfloat16(v.z); tile[e + 3] = __float2bfloat16(v.w);
  }
  __syncthreads();
  const int v0 = threadIdx.x * 4;    // 256 threads x 4 v = 1024
  for (int l = 0; l < L_DIM; ++l) {
    __hip_bfloat16* dst = xT + ((size_t)(b * L_DIM + l) * C_DIM + c) * V_DIM;
    ushort4 u;
    u.x = *(const unsigned short*)&tile[(v0 + 0) * L_DIM + l];
    u.y = *(const unsigned short*)&tile[(v0 + 1) * L_DIM + l];
    u.z = *(const unsigned short*)&tile[(v0 + 2) * L_DIM + l];
    u.w = *(const unsigned short*)&tile[(v0 + 3) * L_DIM + l];
    *(ushort4*)&dst[v0] = u;
  }
}

// ------------- W [32][224] -> Wt[kc 224][o 32] fp32 -----------------------
__global__ __launch_bounds__(256) void transpose_w(
    const float* __restrict__ W, float* __restrict__ Wt) {
  for (int i = threadIdx.x; i < 7168; i += 256) {
    int o = i / 224, cc = i - o * 224;
    Wt[cc * 32 + o] = W[i];
  }
}

// ---------------- async global->LDS helper --------------------------------
__device__ __forceinline__ void gll16(const __hip_bfloat16* g, __hip_bfloat16* l) {
  __builtin_amdgcn_global_load_lds(
      (const __attribute__((address_space(1))) void*)g,
      (__attribute__((address_space(3))) void*)l, 16, 0, 0);
}

// ---------------- MFMA GEMM (128^2, 2-barrier): squares only --------------
// A [M,K] bf16 row-major, Bt [N,K] bf16 row-major, C row-major bf16 [M,N].
template <int MODE>
__global__ __launch_bounds__(256) void gemm_bt(
    const __hip_bfloat16* __restrict__ Abase,
    const __hip_bfloat16* __restrict__ Btbase,
    __hip_bfloat16* __restrict__ Cbase, int M, int N, int K,
    long long aStride, long long bStride, long long cStride) {
  const __hip_bfloat16* A = Abase + (size_t)blockIdx.z * aStride;
  const __hip_bfloat16* Bt = Btbase + (size_t)blockIdx.z * bStride;
  __hip_bfloat16* C = Cbase + (size_t)blockIdx.z * cStride;
  __shared__ __align__(16) __hip_bfloat16 lA[128 * 64];
  __shared__ __align__(16) __hip_bfloat16 lB[128 * 64];
  const int tid = threadIdx.x;
  const int wv = tid >> 6, lane = tid & 63;
  const int wm = wv >> 1, wn = wv & 1;
  const int m0 = blockIdx.y * 128, n0 = blockIdx.x * 128;
  const int lrow = lane >> 3, lcol = lane & 7;  // staging: 8 rows / wave-instr
  const int gcol = lcol ^ (lrow & 7);           // XOR bank swizzle
  const int fr = lane & 15, quad = lane >> 4;   // fragment coords
  const int sw = fr & 7;                        // read-side swizzle key

  floatx4 acc[4][4];
#pragma unroll
  for (int i = 0; i < 4; ++i)
#pragma unroll
    for (int j = 0; j < 4; ++j) acc[i][j] = (floatx4){0.f, 0.f, 0.f, 0.f};

  for (int kt = 0; kt < K; kt += 64) {
    __syncthreads();  // previous tile fully consumed
#pragma unroll
    for (int i = 0; i < 4; ++i) {
      int r0 = (wv * 4 + i) * 8;
      gll16(A + (size_t)(m0 + r0 + lrow) * K + kt + gcol * 8, &lA[r0 * 64]);
      gll16(Bt + (size_t)(n0 + r0 + lrow) * K + kt + gcol * 8, &lB[r0 * 64]);
    }
    __syncthreads();  // drains vmcnt(0): staged data visible
#pragma unroll
    for (int ks = 0; ks < 2; ++ks) {
      const int chunk = (ks * 4 + quad) ^ sw;   // swizzled K-chunk slot
      short8 af[4], bfr[4];
#pragma unroll
      for (int t = 0; t < 4; ++t) {
        af[t] = *(const short8*)&lA[(wm * 64 + t * 16 + fr) * 64 + chunk * 8];
        bfr[t] = *(const short8*)&lB[(wn * 64 + t * 16 + fr) * 64 + chunk * 8];
      }
#pragma unroll
      for (int i = 0; i < 4; ++i)
#pragma unroll
        for (int j = 0; j < 4; ++j)
          acc[i][j] = __builtin_amdgcn_mfma_f32_16x16x32_bf16(af[i], bfr[j], acc[i][j], 0, 0, 0);
    }
  }
  // epilogue: C/D layout col=lane&15, row=quad*4+reg (m89-verified)
#pragma unroll
  for (int i = 0; i < 4; ++i) {
#pragma unroll
    for (int j = 0; j < 4; ++j) {
      int mb = m0 + wm * 64 + i * 16 + quad * 4;
      int n = n0 + wn * 64 + j * 16 + fr;
#pragma unroll
      for (int r = 0; r < 4; ++r) {
        int m = mb + r;
        float val = acc[i][j][r];
        size_t idx;
        if (MODE == 0) {
          idx = (size_t)m * N + n;
        } else {
          int c = m & 31, bl = m >> 5, k = n >> 10, w = n & 1023;
          idx = (((size_t)bl * 6 + k) * 32 + c) * 1024 + w;
        }
        C[idx] = __float2bfloat16(val);
      }
    }
  }
}

// ------------- main diffusion GEMM: 256x128, 4 waves, 2 blocks/CU ---------
// (unchanged from R4 -- control for this round)
__global__ __launch_bounds__(256, 2) void gemm256(
    const __hip_bfloat16* __restrict__ A,
    const __hip_bfloat16* __restrict__ Bt,
    __hip_bfloat16* __restrict__ C) {
  constexpr int K = 1024;
  constexpr int NH = K / 32;  // 32 K-steps
  __shared__ __align__(16) __hip_bfloat16 sA[3][256 * 32];  // 16 KB/unit
  __shared__ __align__(16) __hip_bfloat16 sB[3][128 * 32];  //  8 KB/unit
  const int tid = threadIdx.x;
  const int wv = tid >> 6, lane = tid & 63;
  const int wm = wv >> 1, wn = wv & 1;          // 2x2 wave grid, 128x64/wave
  const int fr = lane & 15, quad = lane >> 4;
  const int rslot = (quad ^ ((fr >> 1) & 3)) << 3;   // swizzled 8-elem slot
  const int aoff = (wm * 128 + fr) * 32 + rslot;     // A-frag elem offset
  const int boff = (wn * 64 + fr) * 32 + rslot;      // B-frag elem offset
  const int m0 = blockIdx.y * 256, n0 = blockIdx.x * 128;
  const int gch = ((lane & 3) ^ ((lane >> 3) & 3)) << 3;
  const __hip_bfloat16* Ag = A + (size_t)(m0 + wv * 16 + (lane >> 2)) * K + gch;
  const __hip_bfloat16* Bg = Bt + (size_t)(n0 + wv * 16 + (lane >> 2)) * K + gch;
  const int sb = (wv * 16) * 32;                     // LDS elem base per wave

  floatx4 acc[8][4];
#pragma unroll
  for (int i = 0; i < 8; ++i)
#pragma unroll
    for (int j = 0; j < 4; ++j) acc[i][j] = (floatx4){0.f, 0.f, 0.f, 0.f};

#define STAGE(hp, ur)                                                        \
  {                                                                          \
    _Pragma("unroll") for (int j = 0; j < 4; ++j)                            \
        gll16(Ag + (size_t)(j * 64) * K + (hp) * 32, &sA[ur][sb + j * 2048]);\
    _Pragma("unroll") for (int j = 0; j < 2; ++j)                            \
        gll16(Bg + (size_t)(j * 64) * K + (hp) * 32, &sB[ur][sb + j * 2048]);\
  }

  STAGE(0, 0)
  STAGE(1, 1)
  asm volatile("s_waitcnt vmcnt(6)" ::: "memory");   // step 0 resident
  __builtin_amdgcn_s_barrier();

  int u = 0, us = 2;
  for (int h = 0; h < NH; ++h) {
    short8 af[8], bf[4];
#pragma unroll
    for (int j = 0; j < 4; ++j) bf[j] = *(const short8*)&sB[u][boff + j * 512];
#pragma unroll
    for (int i = 0; i < 8; ++i) af[i] = *(const short8*)&sA[u][aoff + i * 512];
    if (h < NH - 2) STAGE(h + 2, us)
    __builtin_amdgcn_s_setprio(1);
#pragma unroll
    for (int i = 0; i < 8; ++i)
#pragma unroll
      for (int j = 0; j < 4; ++j)
        acc[i][j] = __builtin_amdgcn_mfma_f32_16x16x32_bf16(af[i], bf[j], acc[i][j], 0, 0, 0);
    __builtin_amdgcn_s_setprio(0);
    if (h < NH - 2) {
      asm volatile("s_waitcnt vmcnt(6)" ::: "memory");  // step h+1 resident
    } else if (h == NH - 2) {
      asm volatile("s_waitcnt vmcnt(0)" ::: "memory");
    }
    __builtin_amdgcn_s_barrier();
    u = (u == 2) ? 0 : u + 1;
    us = (us == 2) ? 0 : us + 1;
  }
#undef STAGE

  // epilogue: R-layout scatter (same mapping as gemm_bt<1>)
#pragma unroll
  for (int i = 0; i < 8; ++i) {
#pragma unroll
    for (int j = 0; j < 4; ++j) {
      int mb = m0 + wm * 128 + i * 16 + quad * 4;
      int n = n0 + wn * 64 + j * 16 + fr;
      int k = n >> 10, w = n & 1023;
#pragma unroll
      for (int r = 0; r < 4; ++r) {
        int m = mb + r;
        int c = m & 31, bl = m >> 5;
        size_t idx = (((size_t)bl * 6 + k) * 32 + c) * 1024 + w;
        C[idx] = __float2bfloat16(acc[i][j][r]);
      }
    }
  }
}

// ---------------- mix: out = W * concat(x, hops) + b ----------------------
// Weights come from global Wt[kc][o] via wave-uniform float4 loads (L1/K$-
// hot, zero LDS) instead of per-lane LDS broadcast reads. LDS = data tile
// only (48 KB) -> 3 blocks/CU.
__global__ __launch_bounds__(256, 3) void mix_kernel(
    const __hip_bfloat16* __restrict__ R, const __hip_bfloat16* __restrict__ xT,
    const float* __restrict__ Wt, const float* __restrict__ bias,
    float* __restrict__ out) {
  const int b = blockIdx.y, wt = blockIdx.x;
  const int tid = threadIdx.x;
  __shared__ __align__(16) __hip_bfloat16 tile[L_DIM * C_DIM * 64];  // [l][c][w64]
  float acc[3][32];
#pragma unroll
  for (int pt = 0; pt < 3; ++pt)
#pragma unroll
    for (int o = 0; o < 32; ++o) acc[pt][o] = bias[o];
  int wloc[3], ll[3];
#pragma unroll
  for (int pt = 0; pt < 3; ++pt) {
    int wl = tid + pt * 256;
    wloc[pt] = wl / 12;
    ll[pt] = wl - wloc[pt] * 12;
  }
  const int w0 = wt * 64;
  for (int k = 0; k < 7; ++k) {
    __syncthreads();
    const __hip_bfloat16* srcp = (k < 6) ? R : xT;
    const int rps = (k < 6) ? 192 : 32;  // rows per (b,l)
    const int ko = (k < 6) ? k * 32 : 0;
#pragma unroll
    for (int i = 0; i < 24; ++i) {       // 6144 ushort4 chunks
      int q = tid + i * 256;
      int rr = q >> 4, ci = q & 15;      // rr = l*32+c
      int l = rr >> 5, c = rr & 31;
      size_t rowg = (size_t)(b * L_DIM + l) * rps + ko + c;
      *(ushort4*)&tile[rr * 64 + ci * 4] =
          *(const ushort4*)&srcp[rowg * V_DIM + w0 + ci * 4];
    }
    __syncthreads();
    const float* Wp = &Wt[((k < 6) ? (k + 1) : 0) * 1024];
    const int base0 = ll[0] * 2048 + wloc[0];
    const int base1 = ll[1] * 2048 + wloc[1];
    const int base2 = ll[2] * 2048 + wloc[2];
#pragma unroll 4
    for (int c = 0; c < 32; ++c) {
      float v0 = __bfloat162float(tile[base0 + c * 64]);
      float v1 = __bfloat162float(tile[base1 + c * 64]);
      float v2 = __bfloat162float(tile[base2 + c * 64]);
      const float4* wq = (const float4*)(Wp + c * 32);  // uniform address
#pragma unroll
      for (int hh = 0; hh < 2; ++hh) {
        float wv[16];
        *(float4*)&wv[0]  = wq[hh * 4 + 0];
        *(float4*)&wv[4]  = wq[hh * 4 + 1];
        *(float4*)&wv[8]  = wq[hh * 4 + 2];
        *(float4*)&wv[12] = wq[hh * 4 + 3];
#pragma unroll
        for (int o = 0; o < 16; ++o) {
          float w = wv[o];
          acc[0][hh * 16 + o] += w * v0;
          acc[1][hh * 16 + o] += w * v1;
          acc[2][hh * 16 + o] += w * v2;
        }
      }
    }
  }
  const size_t obase = (size_t)b * (32 * V_DIM * L_DIM) + (size_t)w0 * L_DIM;
#pragma unroll
  for (int o = 0; o < 32; ++o) {
    size_t base = obase + (size_t)o * (V_DIM * L_DIM);
    out[base + tid] = acc[0][o];
    out[base + tid + 256] = acc[1][o];
    out[base + tid + 512] = acc[2][o];
  }
}

// --------------------------- launcher ------------------------------------
extern "C" void kernel_launch(void* const* d_in, const int* in_sizes, int n_in,
                              void* d_out, int out_size, void* d_ws,
                              size_t ws_size, hipStream_t stream) {
  const float* x = (const float*)d_in[0];
  const float* A1 = (const float*)d_in[1];
  const float* A2 = (const float*)d_in[2];
  const float* nv1 = (const float*)d_in[3];
  const float* nv2 = (const float*)d_in[4];
  const float* W = (const float*)d_in[5];
  const float* bias = (const float*)d_in[6];
  float* out = (float*)d_out;

  char* ws = (char*)d_ws;
  // ws layout (bytes): R 301,989,888 | xT 50,331,648 | BtCat 12,582,912 |
  //                    As 6,291,456 | adp 4,194,304   => total ~375.4 MB
  // Wt (28 KB fp32) overlays the As region (dead after the squares GEMM).
  __hip_bfloat16* R = (__hip_bfloat16*)(ws + 0);
  __hip_bfloat16* xT = (__hip_bfloat16*)(ws + 301989888ull);
  __hip_bfloat16* BtCat = (__hip_bfloat16*)(ws + 352321536ull);
  __hip_bfloat16* As = (__hip_bfloat16*)(ws + 364904448ull);
  float* adp = (float*)(ws + 371195904ull);
  float* Wt = (float*)(ws + 364904448ull);  // reuses As after step 3

  // 1. adaptive adjacency
  adp_kernel<<<dim3(1024), dim3(128), 0, stream>>>(nv1, nv2, adp);
  // 2. bf16 casts: straight (As) + transposed (BtCat slices 0,2,4)
  cast_transpose<<<dim3(16, 16, 3), dim3(256), 0, stream>>>(A1, A2, adp, As, BtCat);
  // 3. squares: BtCat slice 2z+1 = (a^2)^T = At @ As^T   (M=N=K=1024)
  gemm_bt<0><<<dim3(8, 8, 3), dim3(256), 0, stream>>>(
      BtCat, As, BtCat + 1048576ull, 1024, 1024, 1024,
      2097152ll, 1048576ll, 2097152ll);
  // 3b. weight transpose into dead As region
  transpose_w<<<dim3(1), dim3(256), 0, stream>>>(W, Wt);
  // 4. x -> xT bf16
  transpose_x_k<<<dim3(2048), dim3(256), 0, stream>>>(x, xT);
  // 5. main diffusion GEMM: R = xT @ BtCat^T  (M=24576, N=6144, K=1024)
  gemm256<<<dim3(48, 96), dim3(256), 0, stream>>>(xT, BtCat, R);
  // 6. channel mix + bias -> out
  mix_kernel<<<dim3(16, 64), dim3(256), 0, stream>>>(R, xT, Wt, bias, out);
}

// Round 5
// 712.264 us; speedup vs baseline: 1.5667x; 1.5667x over previous
//
#include <hip/hip_runtime.h>
#include <hip/hip_bf16.h>

// Problem constants (fixed by reference): B=64, C=32, V=1024, L=12, ORDER=2
// Decomposition:
//   adp = softmax(relu(nv1@nv2), axis=1)
//   Bt_cat[6][1024][1024] bf16:  slice k, row w, col v = G_k[v][w]
//     G = {A1, A1^2, A2, A2^2, adp, adp^2}
//   xT bf16 rows m=(b*12+l)*32+c, cols v   (row-major K=1024)
//   R'[bl][w][kc=k*32+c] bf16 = hop value (b,c,w,l) for support k
//   out[b,o,w,l] = bias[o] + W[:,0:32]@x + Σ_k W[:,32(k+1):32(k+2)]@R_k
//
// R6 change: mix rewritten as an MFMA GEMM (mixmm). R5's VMEM "uniform"
// weight loads never scalarized -> latency-bound at 614us (VALU 14%, HBM
// 13%). Structural fix: out_b[o][(w,l)] = W @ H_b is a GEMM with M=32,
// K=224, N=12288; weights live in registers as A-fragments (loaded once,
// zero recurring weight traffic). gemm256's epilogue now scatters into
// R'[bl][w][192] rows-along-kc (ushort4 stores, better than old stride-2KB
// scalars) so mix's B-frags are contiguous 16B gathers; n=(w*12+l) ordering
// makes out stores contiguous. W split hi+lo bf16 (fp32-accurate). x-part
// gathered from xT. mixmm: no LDS, no barriers. ws layout unchanged.

typedef __attribute__((ext_vector_type(8))) short short8;
typedef __attribute__((ext_vector_type(4))) float floatx4;

#define V_DIM 1024
#define L_DIM 12
#define B_DIM 64
#define C_DIM 32

// ---------------- adp: relu + row softmax --------------------------------
__global__ __launch_bounds__(128) void adp_kernel(
    const float* __restrict__ nv1, const float* __restrict__ nv2,
    float* __restrict__ adp) {
  const int v = blockIdx.x, tid = threadIdx.x;
  float n1[10];
#pragma unroll
  for (int i = 0; i < 10; ++i) n1[i] = nv1[v * 10 + i];
  __shared__ float red[128];
  float e[8];
  float lmax = -1e30f;
#pragma unroll
  for (int j = 0; j < 8; ++j) {
    int w = tid + j * 128;
    float s = 0.f;
#pragma unroll
    for (int i = 0; i < 10; ++i) s += n1[i] * nv2[i * V_DIM + w];
    s = fmaxf(s, 0.f);
    e[j] = s;
    lmax = fmaxf(lmax, s);
  }
  red[tid] = lmax; __syncthreads();
  for (int s = 64; s > 0; s >>= 1) {
    if (tid < s) red[tid] = fmaxf(red[tid], red[tid + s]);
    __syncthreads();
  }
  float mx = red[0]; __syncthreads();
  float lsum = 0.f;
#pragma unroll
  for (int j = 0; j < 8; ++j) { e[j] = __expf(e[j] - mx); lsum += e[j]; }
  red[tid] = lsum; __syncthreads();
  for (int s = 64; s > 0; s >>= 1) {
    if (tid < s) red[tid] += red[tid + s];
    __syncthreads();
  }
  float inv = 1.f / red[0];
#pragma unroll
  for (int j = 0; j < 8; ++j) adp[(size_t)v * V_DIM + tid + j * 128] = e[j] * inv;
}

// ------------- cast supports to bf16: straight + transposed ---------------
__global__ __launch_bounds__(256) void cast_transpose(
    const float* __restrict__ A1, const float* __restrict__ A2,
    const float* __restrict__ adp, __hip_bfloat16* __restrict__ As,
    __hip_bfloat16* __restrict__ BtCat) {
  const int z = blockIdx.z;
  const float* src = (z == 0) ? A1 : (z == 1) ? A2 : adp;
  __hip_bfloat16* sdst = As + (size_t)z * V_DIM * V_DIM;
  __hip_bfloat16* tdst = BtCat + (size_t)(2 * z) * V_DIM * V_DIM;
  __shared__ float tile[64][65];
  const int v0 = blockIdx.y * 64, w0 = blockIdx.x * 64;
  const int tc = threadIdx.x & 15, tr = threadIdx.x >> 4;
#pragma unroll
  for (int i = 0; i < 4; ++i) {
    int r = tr + i * 16;
    float4 val = *(const float4*)(src + (size_t)(v0 + r) * V_DIM + w0 + tc * 4);
    tile[r][tc * 4 + 0] = val.x; tile[r][tc * 4 + 1] = val.y;
    tile[r][tc * 4 + 2] = val.z; tile[r][tc * 4 + 3] = val.w;
    __hip_bfloat16* sp = sdst + (size_t)(v0 + r) * V_DIM + w0 + tc * 4;
    sp[0] = __float2bfloat16(val.x); sp[1] = __float2bfloat16(val.y);
    sp[2] = __float2bfloat16(val.z); sp[3] = __float2bfloat16(val.w);
  }
  __syncthreads();
#pragma unroll
  for (int i = 0; i < 4; ++i) {
    int r = tr + i * 16;  // output row = w0 + r
    __hip_bfloat16* tp = tdst + (size_t)(w0 + r) * V_DIM + v0 + tc * 4;
#pragma unroll
    for (int j = 0; j < 4; ++j) tp[j] = __float2bfloat16(tile[tc * 4 + j][r]);
  }
}

// ------------- x [B,C,V,L] fp32 -> xT bf16 rows (b*12+l)*32+c -------------
__global__ __launch_bounds__(256) void transpose_x_k(
    const float* __restrict__ x, __hip_bfloat16* __restrict__ xT) {
  const int bc = blockIdx.x;         // b*32+c
  const int b = bc >> 5, c = bc & 31;
  __shared__ __align__(16) __hip_bfloat16 tile[V_DIM * L_DIM];  // idx v*12+l
  const float4* src = (const float4*)(x + (size_t)bc * (V_DIM * L_DIM));
#pragma unroll
  for (int i = 0; i < 12; ++i) {
    int idx = threadIdx.x + i * 256;  // 3072 float4
    float4 v = src[idx];
    int e = idx * 4;
    tile[e + 0] = __float2bfloat16(v.x); tile[e + 1] = __float2bfloat16(v.y);
    tile[e + 2] = __float2bfloat16(v.z); tile[e + 3] = __float2bfloat16(v.w);
  }
  __syncthreads();
  const int v0 = threadIdx.x * 4;    // 256 threads x 4 v = 1024
  for (int l = 0; l < L_DIM; ++l) {
    __hip_bfloat16* dst = xT + ((size_t)(b * L_DIM + l) * C_DIM + c) * V_DIM;
    ushort4 u;
    u.x = *(const unsigned short*)&tile[(v0 + 0) * L_DIM + l];
    u.y = *(const unsigned short*)&tile[(v0 + 1) * L_DIM + l];
    u.z = *(const unsigned short*)&tile[(v0 + 2) * L_DIM + l];
    u.w = *(const unsigned short*)&tile[(v0 + 3) * L_DIM + l];
    *(ushort4*)&dst[v0] = u;
  }
}

// ------------- W [32][224] -> Wre hi/lo bf16 [32][224], cols [hops|x] -----
// Wre col cc<192 -> W col 32+cc (hop groups k=0..5); cc>=192 -> W col cc-192
// (the x group p=0). hi = bf16(w), lo = bf16(w - hi): hi+lo ~= fp32 weight.
__global__ __launch_bounds__(256) void prep_w(
    const float* __restrict__ W, __hip_bfloat16* __restrict__ Whi,
    __hip_bfloat16* __restrict__ Wlo) {
  for (int i = threadIdx.x; i < 32 * 224; i += 256) {
    int o = i / 224, cc = i - o * 224;
    int src = (cc < 192) ? (32 + cc) : (cc - 192);
    float w = W[o * 224 + src];
    __hip_bfloat16 h = __float2bfloat16(w);
    Whi[i] = h;
    Wlo[i] = __float2bfloat16(w - __bfloat162float(h));
  }
}

// ---------------- async global->LDS helper --------------------------------
__device__ __forceinline__ void gll16(const __hip_bfloat16* g, __hip_bfloat16* l) {
  __builtin_amdgcn_global_load_lds(
      (const __attribute__((address_space(1))) void*)g,
      (__attribute__((address_space(3))) void*)l, 16, 0, 0);
}

// ---------------- MFMA GEMM (128^2, 2-barrier): squares only --------------
// A [M,K] bf16 row-major, Bt [N,K] bf16 row-major, C row-major bf16 [M,N].
template <int MODE>
__global__ __launch_bounds__(256) void gemm_bt(
    const __hip_bfloat16* __restrict__ Abase,
    const __hip_bfloat16* __restrict__ Btbase,
    __hip_bfloat16* __restrict__ Cbase, int M, int N, int K,
    long long aStride, long long bStride, long long cStride) {
  const __hip_bfloat16* A = Abase + (size_t)blockIdx.z * aStride;
  const __hip_bfloat16* Bt = Btbase + (size_t)blockIdx.z * bStride;
  __hip_bfloat16* C = Cbase + (size_t)blockIdx.z * cStride;
  __shared__ __align__(16) __hip_bfloat16 lA[128 * 64];
  __shared__ __align__(16) __hip_bfloat16 lB[128 * 64];
  const int tid = threadIdx.x;
  const int wv = tid >> 6, lane = tid & 63;
  const int wm = wv >> 1, wn = wv & 1;
  const int m0 = blockIdx.y * 128, n0 = blockIdx.x * 128;
  const int lrow = lane >> 3, lcol = lane & 7;  // staging: 8 rows / wave-instr
  const int gcol = lcol ^ (lrow & 7);           // XOR bank swizzle
  const int fr = lane & 15, quad = lane >> 4;   // fragment coords
  const int sw = fr & 7;                        // read-side swizzle key

  floatx4 acc[4][4];
#pragma unroll
  for (int i = 0; i < 4; ++i)
#pragma unroll
    for (int j = 0; j < 4; ++j) acc[i][j] = (floatx4){0.f, 0.f, 0.f, 0.f};

  for (int kt = 0; kt < K; kt += 64) {
    __syncthreads();  // previous tile fully consumed
#pragma unroll
    for (int i = 0; i < 4; ++i) {
      int r0 = (wv * 4 + i) * 8;
      gll16(A + (size_t)(m0 + r0 + lrow) * K + kt + gcol * 8, &lA[r0 * 64]);
      gll16(Bt + (size_t)(n0 + r0 + lrow) * K + kt + gcol * 8, &lB[r0 * 64]);
    }
    __syncthreads();  // drains vmcnt(0): staged data visible
#pragma unroll
    for (int ks = 0; ks < 2; ++ks) {
      const int chunk = (ks * 4 + quad) ^ sw;   // swizzled K-chunk slot
      short8 af[4], bfr[4];
#pragma unroll
      for (int t = 0; t < 4; ++t) {
        af[t] = *(const short8*)&lA[(wm * 64 + t * 16 + fr) * 64 + chunk * 8];
        bfr[t] = *(const short8*)&lB[(wn * 64 + t * 16 + fr) * 64 + chunk * 8];
      }
#pragma unroll
      for (int i = 0; i < 4; ++i)
#pragma unroll
        for (int j = 0; j < 4; ++j)
          acc[i][j] = __builtin_amdgcn_mfma_f32_16x16x32_bf16(af[i], bfr[j], acc[i][j], 0, 0, 0);
    }
  }
  // epilogue: C/D layout col=lane&15, row=quad*4+reg (m89-verified)
#pragma unroll
  for (int i = 0; i < 4; ++i) {
#pragma unroll
    for (int j = 0; j < 4; ++j) {
      int mb = m0 + wm * 64 + i * 16 + quad * 4;
      int n = n0 + wn * 64 + j * 16 + fr;
#pragma unroll
      for (int r = 0; r < 4; ++r) {
        int m = mb + r;
        C[(size_t)m * N + n] = __float2bfloat16(acc[i][j][r]);
      }
    }
  }
}

// ------------- main diffusion GEMM: 256x128, 4 waves, 2 blocks/CU ---------
// Pipeline unchanged from R4 (proven 318us). Epilogue now scatters into
// R'[bl][w][kc] rows-along-kc with ushort4 stores (4 consecutive c).
__global__ __launch_bounds__(256, 2) void gemm256(
    const __hip_bfloat16* __restrict__ A,
    const __hip_bfloat16* __restrict__ Bt,
    __hip_bfloat16* __restrict__ Rp) {
  constexpr int K = 1024;
  constexpr int NH = K / 32;  // 32 K-steps
  __shared__ __align__(16) __hip_bfloat16 sA[3][256 * 32];  // 16 KB/unit
  __shared__ __align__(16) __hip_bfloat16 sB[3][128 * 32];  //  8 KB/unit
  const int tid = threadIdx.x;
  const int wv = tid >> 6, lane = tid & 63;
  const int wm = wv >> 1, wn = wv & 1;          // 2x2 wave grid, 128x64/wave
  const int fr = lane & 15, quad = lane >> 4;
  const int rslot = (quad ^ ((fr >> 1) & 3)) << 3;   // swizzled 8-elem slot
  const int aoff = (wm * 128 + fr) * 32 + rslot;     // A-frag elem offset
  const int boff = (wn * 64 + fr) * 32 + rslot;      // B-frag elem offset
  const int m0 = blockIdx.y * 256, n0 = blockIdx.x * 128;
  const int gch = ((lane & 3) ^ ((lane >> 3) & 3)) << 3;
  const __hip_bfloat16* Ag = A + (size_t)(m0 + wv * 16 + (lane >> 2)) * K + gch;
  const __hip_bfloat16* Bg = Bt + (size_t)(n0 + wv * 16 + (lane >> 2)) * K + gch;
  const int sb = (wv * 16) * 32;                     // LDS elem base per wave

  floatx4 acc[8][4];
#pragma unroll
  for (int i = 0; i < 8; ++i)
#pragma unroll
    for (int j = 0; j < 4; ++j) acc[i][j] = (floatx4){0.f, 0.f, 0.f, 0.f};

#define STAGE(hp, ur)                                                        \
  {                                                                          \
    _Pragma("unroll") for (int j = 0; j < 4; ++j)                            \
        gll16(Ag + (size_t)(j * 64) * K + (hp) * 32, &sA[ur][sb + j * 2048]);\
    _Pragma("unroll") for (int j = 0; j < 2; ++j)                            \
        gll16(Bg + (size_t)(j * 64) * K + (hp) * 32, &sB[ur][sb + j * 2048]);\
  }

  STAGE(0, 0)
  STAGE(1, 1)
  asm volatile("s_waitcnt vmcnt(6)" ::: "memory");   // step 0 resident
  __builtin_amdgcn_s_barrier();

  int u = 0, us = 2;
  for (int h = 0; h < NH; ++h) {
    short8 af[8], bf[4];
#pragma unroll
    for (int j = 0; j < 4; ++j) bf[j] = *(const short8*)&sB[u][boff + j * 512];
#pragma unroll
    for (int i = 0; i < 8; ++i) af[i] = *(const short8*)&sA[u][aoff + i * 512];
    if (h < NH - 2) STAGE(h + 2, us)
    __builtin_amdgcn_s_setprio(1);
#pragma unroll
    for (int i = 0; i < 8; ++i)
#pragma unroll
      for (int j = 0; j < 4; ++j)
        acc[i][j] = __builtin_amdgcn_mfma_f32_16x16x32_bf16(af[i], bf[j], acc[i][j], 0, 0, 0);
    __builtin_amdgcn_s_setprio(0);
    if (h < NH - 2) {
      asm volatile("s_waitcnt vmcnt(6)" ::: "memory");  // step h+1 resident
    } else if (h == NH - 2) {
      asm volatile("s_waitcnt vmcnt(0)" ::: "memory");
    }
    __builtin_amdgcn_s_barrier();
    u = (u == 2) ? 0 : u + 1;
    us = (us == 2) ? 0 : us + 1;
  }
#undef STAGE

  // epilogue: R' scatter. m -> (bl, c), n -> (k, w); 4 consecutive c = 8B.
#pragma unroll
  for (int i = 0; i < 8; ++i) {
#pragma unroll
    for (int j = 0; j < 4; ++j) {
      int mb = m0 + wm * 128 + i * 16 + quad * 4;
      int n = n0 + wn * 64 + j * 16 + fr;
      int k = n >> 10, w = n & 1023;
      int bl = mb >> 5, c0 = mb & 31;
      ushort4 pk;
      unsigned short* pp = (unsigned short*)&pk;
#pragma unroll
      for (int r = 0; r < 4; ++r) {
        __hip_bfloat16 hv = __float2bfloat16(acc[i][j][r]);
        pp[r] = *(unsigned short*)&hv;
      }
      *(ushort4*)&Rp[((size_t)bl * 1024 + w) * 192 + k * 32 + c0] = pk;
    }
  }
}

// ---------------- mixmm: out = W @ concat(hops, x) + b  (MFMA) ------------
// Per b: out_b[o][n=(w*12+l)] = Σ_kc Wre[o][kc] H[kc][n],
//   kc<192: H row = R'[b*12+l][w][kc] (contiguous along kc);
//   kc>=192: H = xT[(b*12+l)*32 + (kc-192)][w].
// A-frags = Wre rows (hi+lo bf16, fp32-accurate), B-frags = 16B gathers.
// No LDS, no barriers. C layout col=lane&15 (n), row=quad*4+r (o) -> out
// stores are 64B-contiguous segments.
__global__ __launch_bounds__(256) void mixmm(
    const __hip_bfloat16* __restrict__ Rp, const __hip_bfloat16* __restrict__ xT,
    const __hip_bfloat16* __restrict__ Whi, const __hip_bfloat16* __restrict__ Wlo,
    const float* __restrict__ bias, float* __restrict__ out) {
  const int b = blockIdx.y;
  const int tid = threadIdx.x, wv = tid >> 6, lane = tid & 63;
  const int fr = lane & 15, quad = lane >> 4;
  const int n_base = blockIdx.x * 512 + wv * 128;

  // per-Nfrag lane coordinates (n = w*12 + l)
  unsigned int rb[8], xb[8];
#pragma unroll
  for (int nf = 0; nf < 8; ++nf) {
    int n = n_base + nf * 16 + fr;
    int w = n / 12, l = n - w * 12;
    int bl = b * L_DIM + l;
    rb[nf] = ((unsigned)bl * 1024 + w) * 192 + quad * 8;  // R' elem index
    xb[nf] = (unsigned)bl * 32 * 1024 + w;                // xT base (c=0)
  }
  const int arow0 = fr * 224 + quad * 8;          // Wre row o=fr
  const int arow1 = (16 + fr) * 224 + quad * 8;   // o=16+fr

  floatx4 acc[2][8];
#pragma unroll
  for (int mt = 0; mt < 2; ++mt)
#pragma unroll
    for (int nf = 0; nf < 8; ++nf) acc[mt][nf] = (floatx4){0.f, 0.f, 0.f, 0.f};

#pragma unroll
  for (int ks = 0; ks < 6; ++ks) {
    short8 bfr[8];
#pragma unroll
    for (int nf = 0; nf < 8; ++nf)
      bfr[nf] = *(const short8*)&Rp[rb[nf] + ks * 32];
    short8 a0h = *(const short8*)&Whi[arow0 + ks * 32];
    short8 a1h = *(const short8*)&Whi[arow1 + ks * 32];
    short8 a0l = *(const short8*)&Wlo[arow0 + ks * 32];
    short8 a1l = *(const short8*)&Wlo[arow1 + ks * 32];
#pragma unroll
    for (int nf = 0; nf < 8; ++nf) {
      acc[0][nf] = __builtin_amdgcn_mfma_f32_16x16x32_bf16(a0h, bfr[nf], acc[0][nf], 0, 0, 0);
      acc[1][nf] = __builtin_amdgcn_mfma_f32_16x16x32_bf16(a1h, bfr[nf], acc[1][nf], 0, 0, 0);
      acc[0][nf] = __builtin_amdgcn_mfma_f32_16x16x32_bf16(a0l, bfr[nf], acc[0][nf], 0, 0, 0);
      acc[1][nf] = __builtin_amdgcn_mfma_f32_16x16x32_bf16(a1l, bfr[nf], acc[1][nf], 0, 0, 0);
    }
  }
  {  // x group (kc 192..223): gather 8 strided ushorts from xT
    short8 bfr[8];
#pragma unroll
    for (int nf = 0; nf < 8; ++nf) {
      short8 v;
#pragma unroll
      for (int e = 0; e < 8; ++e)
        v[e] = *(const short*)&xT[(size_t)xb[nf] + (unsigned)(quad * 8 + e) * 1024];
      bfr[nf] = v;
    }
    short8 a0h = *(const short8*)&Whi[arow0 + 192];
    short8 a1h = *(const short8*)&Whi[arow1 + 192];
    short8 a0l = *(const short8*)&Wlo[arow0 + 192];
    short8 a1l = *(const short8*)&Wlo[arow1 + 192];
#pragma unroll
    for (int nf = 0; nf < 8; ++nf) {
      acc[0][nf] = __builtin_amdgcn_mfma_f32_16x16x32_bf16(a0h, bfr[nf], acc[0][nf], 0, 0, 0);
      acc[1][nf] = __builtin_amdgcn_mfma_f32_16x16x32_bf16(a1h, bfr[nf], acc[1][nf], 0, 0, 0);
      acc[0][nf] = __builtin_amdgcn_mfma_f32_16x16x32_bf16(a0l, bfr[nf], acc[0][nf], 0, 0, 0);
      acc[1][nf] = __builtin_amdgcn_mfma_f32_16x16x32_bf16(a1l, bfr[nf], acc[1][nf], 0, 0, 0);
    }
  }
  // epilogue: out[b][o][n] + bias; 16 contiguous n per quad-segment
  float bv[2][4];
#pragma unroll
  for (int mt = 0; mt < 2; ++mt)
#pragma unroll
    for (int r = 0; r < 4; ++r) bv[mt][r] = bias[mt * 16 + quad * 4 + r];
#pragma unroll
  for (int mt = 0; mt < 2; ++mt)
#pragma unroll
    for (int nf = 0; nf < 8; ++nf) {
      float* op = out + ((size_t)b * 32 + mt * 16 + quad * 4) * 12288 +
                  n_base + nf * 16 + fr;
#pragma unroll
      for (int r = 0; r < 4; ++r)
        op[(size_t)r * 12288] = acc[mt][nf][r] + bv[mt][r];
    }
}

// --------------------------- launcher ------------------------------------
extern "C" void kernel_launch(void* const* d_in, const int* in_sizes, int n_in,
                              void* d_out, int out_size, void* d_ws,
                              size_t ws_size, hipStream_t stream) {
  const float* x = (const float*)d_in[0];
  const float* A1 = (const float*)d_in[1];
  const float* A2 = (const float*)d_in[2];
  const float* nv1 = (const float*)d_in[3];
  const float* nv2 = (const float*)d_in[4];
  const float* W = (const float*)d_in[5];
  const float* bias = (const float*)d_in[6];
  float* out = (float*)d_out;

  char* ws = (char*)d_ws;
  // ws layout (bytes): R' 301,989,888 | xT 50,331,648 | BtCat 12,582,912 |
  //                    As 6,291,456 | adp 4,194,304   => total ~375.4 MB
  // Wre hi/lo (28 KB bf16) overlay the As region (dead after squares GEMM).
  __hip_bfloat16* Rp = (__hip_bfloat16*)(ws + 0);
  __hip_bfloat16* xT = (__hip_bfloat16*)(ws + 301989888ull);
  __hip_bfloat16* BtCat = (__hip_bfloat16*)(ws + 352321536ull);
  __hip_bfloat16* As = (__hip_bfloat16*)(ws + 364904448ull);
  float* adp = (float*)(ws + 371195904ull);
  __hip_bfloat16* Whi = (__hip_bfloat16*)(ws + 364904448ull);  // reuses As
  __hip_bfloat16* Wlo = Whi + 32 * 224;

  // 1. adaptive adjacency
  adp_kernel<<<dim3(1024), dim3(128), 0, stream>>>(nv1, nv2, adp);
  // 2. bf16 casts: straight (As) + transposed (BtCat slices 0,2,4)
  cast_transpose<<<dim3(16, 16, 3), dim3(256), 0, stream>>>(A1, A2, adp, As, BtCat);
  // 3. squares: BtCat slice 2z+1 = (a^2)^T = At @ As^T   (M=N=K=1024)
  gemm_bt<0><<<dim3(8, 8, 3), dim3(256), 0, stream>>>(
      BtCat, As, BtCat + 1048576ull, 1024, 1024, 1024,
      2097152ll, 1048576ll, 2097152ll);
  // 3b. weight prep (hi/lo bf16, reordered cols) into dead As region
  prep_w<<<dim3(1), dim3(256), 0, stream>>>(W, Whi, Wlo);
  // 4. x -> xT bf16
  transpose_x_k<<<dim3(2048), dim3(256), 0, stream>>>(x, xT);
  // 5. main diffusion GEMM: R' = xT @ BtCat^T  (M=24576, N=6144, K=1024)
  gemm256<<<dim3(48, 96), dim3(256), 0, stream>>>(xT, BtCat, Rp);
  // 6. channel mix as MFMA GEMM (M=32, K=224, N=12288 per b)
  mixmm<<<dim3(24, 64), dim3(256), 0, stream>>>(Rp, xT, Whi, Wlo, bias, out);
}